// Round 9
// baseline (158.655 us; speedup 1.0000x reference)
//
#include <hip/hip_runtime.h>
#include <hip/hip_fp16.h>

#define Nn 2048
#define Ff 64
#define Uu 64
#define NT 256
#define CW 256          // chunk width (cols)
#define NCH 8           // chunks per row (2048/256)

typedef _Float16 f16x4 __attribute__((ext_vector_type(4)));
typedef _Float16 f16x8 __attribute__((ext_vector_type(8)));
typedef float    f32x4 __attribute__((ext_vector_type(4)));

#define MFMA32(a,b,c) __builtin_amdgcn_mfma_f32_16x16x32_f16(a,b,c,0,0,0)
#define G1S 68

// ---- X transpose: Xt[b][f][k] = (f16) X[b][k][f] ----
__global__ __launch_bounds__(256) void transposeX(const float* __restrict__ X,
                                                  _Float16* __restrict__ Xt) {
    __shared__ _Float16 tile[64][65];
    const int b = blockIdx.x, kt = blockIdx.y;
    #pragma unroll
    for (int i = 0; i < 16; ++i) {
        int e  = i * 256 + threadIdx.x;
        int kk = e >> 6, ff = e & 63;
        tile[ff][kk] = (_Float16)X[((size_t)b * Nn + kt * 64 + kk) * Ff + ff];
    }
    __syncthreads();
    #pragma unroll
    for (int i = 0; i < 16; ++i) {
        int e  = i * 256 + threadIdx.x;
        int ff = e >> 6, kk = e & 63;
        Xt[((size_t)b * Ff + ff) * Nn + kt * 64 + kk] = tile[ff][kk];
    }
}

// Producer unit = 1 row x 256 cols; every load = 64 lanes x 16B contiguous.
#define ISSUE_U(Vd,Vw0,Vw1,Vw2,Vg,Vk, C, U) {                 \
    const size_t _o = (size_t)(U) * Nn + (size_t)(C) * CW + (lane << 2); \
    Vd  = *(const float4*)(dP + _o);                          \
    Vw0 = *(const float4*)(wP + 3 * _o);                      \
    Vw1 = *(const float4*)(wP + 3 * _o + 4);                  \
    Vw2 = *(const float4*)(wP + 3 * _o + 8);                  \
    Vg  = *(const float4*)(gP + _o);                          \
    Vk  = *(const float4*)(kP + _o);                          \
}

// exp(fusion)->f16, swizzled LDS write (rows of 512B), register row-sum.
#define CONSUME_U(Vd,Vw0,Vw1,Vw2,Vg,Vk, BUF, U) {                             \
    float _e0 = __expf(fminf(Vd.x*Vw0.x + Vg.x*Vw0.y + Vk.x*Vw0.z, 11.f));    \
    float _e1 = __expf(fminf(Vd.y*Vw0.w + Vg.y*Vw1.x + Vk.y*Vw1.y, 11.f));    \
    float _e2 = __expf(fminf(Vd.z*Vw1.z + Vg.z*Vw1.w + Vk.z*Vw2.x, 11.f));    \
    float _e3 = __expf(fminf(Vd.w*Vw2.y + Vg.w*Vw2.z + Vk.w*Vw2.w, 11.f));    \
    f16x4 _h = {(_Float16)_e0, (_Float16)_e1, (_Float16)_e2, (_Float16)_e3};  \
    rs[U] += (float)_h[0] + (float)_h[1] + (float)_h[2] + (float)_h[3];       \
    const int _ba = (p8 + (U)) * 512 + (lane << 3);                           \
    *(f16x4*)((char*)(BUF) + (_ba ^ (((U) & 7) << 4))) = _h;                  \
}

// Stage one chunk (units 0,1 pre-issued by previous iteration / prologue).
// Pre-issues units 0,1 of chunk C+1 before the barrier when PRE, so the
// producer's HBM stream never drains — even across __syncthreads.
#define STAGE_BODY(BUF, C, PRE) {                          \
    CONSUME_U(Ad,Aw0,Aw1,Aw2,Ag,Ak, BUF, 0);               \
    ISSUE_U(Ad,Aw0,Aw1,Aw2,Ag,Ak, C, 2);                   \
    CONSUME_U(Bd,Bw0,Bw1,Bw2,Bg,Bk, BUF, 1);               \
    ISSUE_U(Bd,Bw0,Bw1,Bw2,Bg,Bk, C, 3);                   \
    CONSUME_U(Ad,Aw0,Aw1,Aw2,Ag,Ak, BUF, 2);               \
    ISSUE_U(Ad,Aw0,Aw1,Aw2,Ag,Ak, C, 4);                   \
    CONSUME_U(Bd,Bw0,Bw1,Bw2,Bg,Bk, BUF, 3);               \
    ISSUE_U(Bd,Bw0,Bw1,Bw2,Bg,Bk, C, 5);                   \
    CONSUME_U(Ad,Aw0,Aw1,Aw2,Ag,Ak, BUF, 4);               \
    ISSUE_U(Ad,Aw0,Aw1,Aw2,Ag,Ak, C, 6);                   \
    CONSUME_U(Bd,Bw0,Bw1,Bw2,Bg,Bk, BUF, 5);               \
    ISSUE_U(Bd,Bw0,Bw1,Bw2,Bg,Bk, C, 7);                   \
    CONSUME_U(Ad,Aw0,Aw1,Aw2,Ag,Ak, BUF, 6);               \
    if (PRE) { ISSUE_U(Ad,Aw0,Aw1,Aw2,Ag,Ak, (C)+1, 0); }  \
    CONSUME_U(Bd,Bw0,Bw1,Bw2,Bg,Bk, BUF, 7);               \
    if (PRE) { ISSUE_U(Bd,Bw0,Bw1,Bw2,Bg,Bk, (C)+1, 1); }  \
}

// Consumer: 8 k-steps over one staged chunk, 2 col-tiles, B from L2 Xt.
#define MFMA_CHUNK(BUF, C) {                                        \
    const char* _bc = (const char*)(BUF);                           \
    const _Float16* _x0 = xB0 + (size_t)(C) * CW;                   \
    const _Float16* _x1 = xB1 + (size_t)(C) * CW;                   \
    _Pragma("unroll")                                               \
    for (int kk = 0; kk < 8; ++kk) {                                \
        const int aa = r * 512 + kk * 64 + kg * 16;                 \
        f16x8 af = *(const f16x8*)(_bc + (aa ^ ((r & 7) << 4)));    \
        f16x8 b0 = *(const f16x8*)(_x0 + kk * 32);                  \
        f16x8 b1 = *(const f16x8*)(_x1 + kk * 32);                  \
        acc0 = MFMA32(af, b0, acc0);                                \
        acc1 = MFMA32(af, b1, acc1);                                \
    }                                                               \
}

// One block = batch b x 16 rows. Waves 0,1 = pure producers (stream fusion
// -> exp -> LDS, 8 rows each, never MFMA). Waves 2,3 = pure consumers
// (MFMA from LDS P + L2-resident Xt, never touch HBM). One barrier per
// chunk; producer stream is continuous across barriers via pre-issue.
__global__ __launch_bounds__(NT, 4) void fused_gcn(
    const _Float16* __restrict__ Xt,  // [B,F,N] f16
    const float* __restrict__ Dyn,    // [B,N,N]
    const float* __restrict__ Wf,     // [B,N,N,3]
    const float* __restrict__ Geo,    // [N,N]
    const float* __restrict__ KLm,    // [N,N]
    const float* __restrict__ Wd,     // [F,U]
    const float* __restrict__ bdv,    // [U]
    float* __restrict__ out)          // [B,N,U]
{
    __shared__ _Float16 Pb[2][16 * CW];    // 2 x 8 KB P chunk buffers
    __shared__ float wsumS[16];
    __shared__ float invS[16];
    __shared__ float g1[16 * G1S];

    const int t    = threadIdx.x;
    const int lane = t & 63;
    const int wid  = t >> 6;
    const int r    = lane & 15;
    const int kg   = lane >> 4;
    const int b    = blockIdx.x >> 7;
    const int n0   = (blockIdx.x & 127) << 4;

    // producer role params (wid 0,1); &1 keeps addresses in-range for all
    const int p  = wid & 1;
    const int p8 = p << 3;
    const float* dP = Dyn + ((size_t)b * Nn + n0 + p8) * Nn;
    const float* wP = Wf  + ((size_t)b * Nn + n0 + p8) * (size_t)Nn * 3;
    const float* gP = Geo + (size_t)(n0 + p8) * Nn;
    const float* kP = KLm + (size_t)(n0 + p8) * Nn;

    // consumer role params (wid 2,3): col-tiles cw*2, cw*2+1
    const int cw = wid & 1;
    const _Float16* xB0 = Xt + (size_t)b * Ff * Nn
                        + (size_t)((cw * 2) * 16 + r) * Nn + (kg << 3);
    const _Float16* xB1 = xB0 + (size_t)16 * Nn;

    float rs[8] = {0.f,0.f,0.f,0.f,0.f,0.f,0.f,0.f};
    f32x4 acc0 = {0.f,0.f,0.f,0.f}, acc1 = {0.f,0.f,0.f,0.f};
    float4 Ad, Aw0, Aw1, Aw2, Ag, Ak;
    float4 Bd, Bw0, Bw1, Bw2, Bg, Bk;

    if (wid < 2) {                      // prologue: prime units 0,1 of chunk 0
        ISSUE_U(Ad,Aw0,Aw1,Aw2,Ag,Ak, 0, 0);
        ISSUE_U(Bd,Bw0,Bw1,Bw2,Bg,Bk, 0, 1);
    }

    #pragma unroll 1
    for (int it = 0; it < NCH + 1; ++it) {
        if (wid < 2) {
            if (it < NCH) STAGE_BODY(&Pb[it & 1][0], it, (it + 1 < NCH));
        } else {
            if (it > 0) MFMA_CHUNK(&Pb[(it - 1) & 1][0], it - 1);
        }
        __syncthreads();
    }

    // ---- row sums (producers own the data) ----
    if (wid < 2) {
        #pragma unroll
        for (int u = 0; u < 8; ++u) {
            float v = rs[u];
            v += __shfl_xor(v, 1, 64);  v += __shfl_xor(v, 2, 64);
            v += __shfl_xor(v, 4, 64);  v += __shfl_xor(v, 8, 64);
            v += __shfl_xor(v, 16, 64); v += __shfl_xor(v, 32, 64);
            if (lane == 0) wsumS[p8 + u] = v;
        }
    }
    __syncthreads();
    if (t < 16) invS[t] = 1.0f / wsumS[t];
    __syncthreads();

    // ---- consumers write normalized G1 tile ----
    if (wid >= 2) {
        #pragma unroll
        for (int i = 0; i < 4; ++i) {
            const int ro = (kg << 2) + i;
            const float inv = invS[ro];
            g1[ro * G1S + (cw * 2) * 16 + r]       = acc0[i] * inv;
            g1[ro * G1S + (cw * 2 + 1) * 16 + r]   = acc1[i] * inv;
        }
    }
    __syncthreads();

    // ---- Dense(64) + tanh: wave wid -> rows wid*4..+3, col = lane ----
    const int row0 = wid << 2;
    const float* g1r = g1 + row0 * G1S;
    float o0 = bdv[lane], o1 = o0, o2 = o0, o3 = o0;
    #pragma unroll 4
    for (int f = 0; f < Ff; ++f) {
        float wdv = Wd[f * Uu + lane];
        o0 += g1r[f]           * wdv;
        o1 += g1r[G1S + f]     * wdv;
        o2 += g1r[2 * G1S + f] * wdv;
        o3 += g1r[3 * G1S + f] * wdv;
    }
    float oo[4] = {o0, o1, o2, o3};
    #pragma unroll
    for (int i = 0; i < 4; ++i) {
        float x  = fminf(fmaxf(oo[i], -15.f), 15.f);
        float ex = __expf(2.f * x);
        out[((size_t)b * Nn + n0 + row0 + i) * Uu + lane] = (ex - 1.f) / (ex + 1.f);
    }
}

extern "C" void kernel_launch(void* const* d_in, const int* in_sizes, int n_in,
                              void* d_out, int out_size, void* d_ws, size_t ws_size,
                              hipStream_t stream) {
    const float* X   = (const float*)d_in[0];
    const float* Dyn = (const float*)d_in[1];
    const float* Wf  = (const float*)d_in[2];
    const float* Geo = (const float*)d_in[3];
    const float* KLm = (const float*)d_in[4];
    const float* Wd  = (const float*)d_in[5];
    const float* bdv = (const float*)d_in[6];
    float* out = (float*)d_out;

    _Float16* Xt = (_Float16*)d_ws;   // 2 MB scratch
    transposeX<<<dim3(8, Nn / 64), dim3(256), 0, stream>>>(X, Xt);
    fused_gcn<<<dim3(8 * (Nn / 16)), dim3(NT), 0, stream>>>(
        Xt, Dyn, Wf, Geo, KLm, Wd, bdv, out);
}

// Round 10
// 127.924 us; speedup vs baseline: 1.2402x; 1.2402x over previous
//
#include <hip/hip_runtime.h>
#include <hip/hip_fp16.h>

#define Nn 2048
#define Ff 64
#define Uu 64
#define NT 256
#define CW 64            // chunk width (cols)
#define NCH 32           // 2048/64
#define G1S 68

typedef _Float16 f16x4 __attribute__((ext_vector_type(4)));
typedef _Float16 f16x8 __attribute__((ext_vector_type(8)));
typedef float    f32x4 __attribute__((ext_vector_type(4)));

#define MFMA32(a,b,c) __builtin_amdgcn_mfma_f32_16x16x32_f16(a,b,c,0,0,0)

// async global->LDS, 16B/lane, per-lane global addr, linear wave-uniform LDS dest
#define GLD16(gp, lp) __builtin_amdgcn_global_load_lds(                      \
    (const __attribute__((address_space(1))) void*)(gp),                     \
    (__attribute__((address_space(3))) void*)(lp), 16, 0, 0)

// ---- X transpose: Xt[b][f][k] = (f16) X[b][k][f] (validated R4-R9) ----
__global__ __launch_bounds__(256) void transposeX(const float* __restrict__ X,
                                                  _Float16* __restrict__ Xt) {
    __shared__ _Float16 tile[64][65];
    const int b = blockIdx.x, kt = blockIdx.y;
    #pragma unroll
    for (int i = 0; i < 16; ++i) {
        int e  = i * 256 + threadIdx.x;
        int kk = e >> 6, ff = e & 63;
        tile[ff][kk] = (_Float16)X[((size_t)b * Nn + kt * 64 + kk) * Ff + ff];
    }
    __syncthreads();
    #pragma unroll
    for (int i = 0; i < 16; ++i) {
        int e  = i * 256 + threadIdx.x;
        int ff = e >> 6, kk = e & 63;
        Xt[((size_t)b * Ff + ff) * Nn + kt * 64 + kk] = tile[ff][kk];
    }
}

// Issue the 6 async loads for this wave's 4 rows of the next chunk, then
// advance the per-lane pointers. Zero VGPR staging; loads stay in flight
// through the exp-pass + MFMA and drain at the chunk-end s_waitcnt.
#define STAGE_ISSUE(P) {                                       \
    char* _db = (char*)&Db[P][0] + wid * 1024;                 \
    char* _gb = (char*)&Gb[P][0] + wid * 1024;                 \
    char* _kb = (char*)&Kb[P][0] + wid * 1024;                 \
    char* _wb = (char*)&Wb[P][0] + wid * 3072;                 \
    GLD16(dG, _db);                                            \
    GLD16(gG, _gb);                                            \
    GLD16(kG, _kb);                                            \
    GLD16(wG0, _wb);                                           \
    GLD16(wG1, _wb + 1024);                                    \
    GLD16(wG2, _wb + 2048);                                    \
    dG += 256; gG += 256; kG += 256;                           \
    wG0 += 768; wG1 += 768; wG2 += 768;                        \
}

__global__ __launch_bounds__(NT, 2) void fused_gcn(
    const _Float16* __restrict__ Xt,  // [B,F,N] f16
    const float* __restrict__ Dyn,    // [B,N,N]
    const float* __restrict__ Wf,     // [B,N,N,3]
    const float* __restrict__ Geo,    // [N,N]
    const float* __restrict__ KLm,    // [N,N]
    const float* __restrict__ Wd,     // [F,U]
    const float* __restrict__ bdv,    // [U]
    float* __restrict__ out)          // [B,N,U]
{
    __shared__ float   Db[2][16 * 64];    // raw D chunk, 2 x 4 KB
    __shared__ float   Wb[2][16 * 192];   // raw W chunk, 2 x 12 KB
    __shared__ float   Gb[2][16 * 64];
    __shared__ float   Kb[2][16 * 64];
    __shared__ _Float16 Pb[2][16 * 64];   // exp(fusion) f16, swizzled
    __shared__ float   g1[16 * G1S];
    __shared__ float   wsumS[16];
    __shared__ float   invS[16];

    const int t    = threadIdx.x;
    const int lane = t & 63;
    const int wid  = t >> 6;
    const int r    = lane & 15;
    const int kg   = lane >> 4;
    const int b    = blockIdx.x >> 7;
    const int n0   = (blockIdx.x & 127) << 4;

    // ---- per-lane global gather pointers (wave owns rows 4*wid..4*wid+3)
    const int lrow = lane >> 4, lq = lane & 15;
    const char* dG = (const char*)(Dyn + ((size_t)b * Nn + n0 + 4 * wid) * Nn)
                     + (size_t)lrow * (Nn * 4) + lq * 16;
    const char* gG = (const char*)(Geo + (size_t)(n0 + 4 * wid) * Nn)
                     + (size_t)lrow * (Nn * 4) + lq * 16;
    const char* kG = (const char*)(KLm + (size_t)(n0 + 4 * wid) * Nn)
                     + (size_t)lrow * (Nn * 4) + lq * 16;
    const char* wbase = (const char*)(Wf + ((size_t)b * Nn + n0 + 4 * wid) * (size_t)Nn * 3);
    // W: 3 x 1KB loads cover 4 rows x 768B linearly; map linear->((row),(colbyte))
    const int lin0 = lane * 16;
    const int lin1 = 1024 + lane * 16;
    const int lin2 = 2048 + lane * 16;
    const int rw0 = (lin0 >= 768) ? 1 : 0;
    const int rw1 = (lin1 >= 1536) ? 2 : 1;
    const int rw2 = (lin2 >= 2304) ? 3 : 2;
    const char* wG0 = wbase + (size_t)rw0 * (Nn * 12) + (lin0 - rw0 * 768);
    const char* wG1 = wbase + (size_t)rw1 * (Nn * 12) + (lin1 - rw1 * 768);
    const char* wG2 = wbase + (size_t)rw2 * (Nn * 12) + (lin2 - rw2 * 768);

    const _Float16* xw = Xt + (size_t)b * Ff * Nn
                       + (size_t)(wid * 16 + r) * Nn + (kg << 3);

    // exp-pass mapping: thread t -> row t>>4, col-quad t&15
    const int erow = t >> 4, eq = t & 15;

    f32x4 acc = {0.f, 0.f, 0.f, 0.f};
    float rs = 0.f;

    // ---- prologue: stage chunk 0, drain, barrier ----
    STAGE_ISSUE(0);
    asm volatile("s_waitcnt vmcnt(0)" ::: "memory");
    __builtin_amdgcn_s_barrier();

    #pragma unroll 1
    for (int c = 0; c < NCH; ++c) {
        const int pc = c & 1;

        // B-frags for this chunk (oldest vmcnt entries -> MFMA waits never
        // drain the async stage queue)
        f16x8 bf0 = *(const f16x8*)(xw);
        f16x8 bf1 = *(const f16x8*)(xw + 32);
        xw += 64;
        __builtin_amdgcn_sched_barrier(0);

        // fire-and-forget stage of chunk c+1
        if (c + 1 < NCH) STAGE_ISSUE(pc ^ 1);
        __builtin_amdgcn_sched_barrier(0);

        // ---- exp-pass on raw chunk c (LDS only) ----
        {
            const float* dd = &Db[pc][erow * 64 + eq * 4];
            const float* gg = &Gb[pc][erow * 64 + eq * 4];
            const float* kk = &Kb[pc][erow * 64 + eq * 4];
            const float* ww = &Wb[pc][erow * 192 + eq * 12];
            float4 dv = *(const float4*)dd;
            float4 gv = *(const float4*)gg;
            float4 kv = *(const float4*)kk;
            float4 w0 = *(const float4*)ww;
            float4 w1 = *(const float4*)(ww + 4);
            float4 w2 = *(const float4*)(ww + 8);
            float e0 = __expf(fminf(dv.x*w0.x + gv.x*w0.y + kv.x*w0.z, 11.f));
            float e1 = __expf(fminf(dv.y*w0.w + gv.y*w1.x + kv.y*w1.y, 11.f));
            float e2 = __expf(fminf(dv.z*w1.z + gv.z*w1.w + kv.z*w2.x, 11.f));
            float e3 = __expf(fminf(dv.w*w2.y + gv.w*w2.z + kv.w*w2.w, 11.f));
            f16x4 h = {(_Float16)e0, (_Float16)e1, (_Float16)e2, (_Float16)e3};
            rs += (float)h[0] + (float)h[1] + (float)h[2] + (float)h[3];
            *(f16x4*)((char*)&Pb[pc][0]
                      + ((erow * 128 + eq * 8) ^ ((erow & 7) << 4))) = h;
        }

        // P visible to all waves: drain DS only (async loads keep flying)
        asm volatile("s_waitcnt lgkmcnt(0)" ::: "memory");
        __builtin_amdgcn_sched_barrier(0);
        __builtin_amdgcn_s_barrier();

        // ---- MFMA: A from swizzled P, B from L2-resident Xt ----
        {
            const char* pbuf = (const char*)&Pb[pc][0];
            f16x8 af0 = *(const f16x8*)(pbuf + ((r * 128 + kg * 16) ^ ((r & 7) << 4)));
            f16x8 af1 = *(const f16x8*)(pbuf + ((r * 128 + 64 + kg * 16) ^ ((r & 7) << 4)));
            acc = MFMA32(af0, bf0, acc);
            acc = MFMA32(af1, bf1, acc);
        }

        // chunk c+1 landed; make it visible
        asm volatile("s_waitcnt vmcnt(0)" ::: "memory");
        __builtin_amdgcn_sched_barrier(0);
        __builtin_amdgcn_s_barrier();
    }

    // ---- row sums: 16 threads per row are one 16-lane group ----
    float v = rs;
    v += __shfl_xor(v, 1, 64); v += __shfl_xor(v, 2, 64);
    v += __shfl_xor(v, 4, 64); v += __shfl_xor(v, 8, 64);
    if ((lane & 15) == 0) wsumS[(wid << 2) + (lane >> 4)] = v;
    __syncthreads();
    if (t < 16) invS[t] = 1.0f / wsumS[t];
    __syncthreads();

    // ---- normalized G1 tile (C layout validated in R6) ----
    #pragma unroll
    for (int i = 0; i < 4; ++i) {
        const int ro = (kg << 2) + i;
        g1[ro * G1S + (wid << 4) + r] = acc[i] * invS[ro];
    }
    __syncthreads();

    // ---- Dense(64) + tanh (R6 verbatim) ----
    const int row0 = wid << 2;
    const float* g1r = g1 + row0 * G1S;
    float o0 = bdv[lane], o1 = o0, o2 = o0, o3 = o0;
    #pragma unroll 4
    for (int f = 0; f < Ff; ++f) {
        float wdv = Wd[f * Uu + lane];
        o0 += g1r[f]           * wdv;
        o1 += g1r[G1S + f]     * wdv;
        o2 += g1r[2 * G1S + f] * wdv;
        o3 += g1r[3 * G1S + f] * wdv;
    }
    float oo[4] = {o0, o1, o2, o3};
    #pragma unroll
    for (int i = 0; i < 4; ++i) {
        float x  = fminf(fmaxf(oo[i], -15.f), 15.f);
        float ex = __expf(2.f * x);
        out[((size_t)b * Nn + n0 + row0 + i) * Uu + lane] = (ex - 1.f) / (ex + 1.f);
    }
}

extern "C" void kernel_launch(void* const* d_in, const int* in_sizes, int n_in,
                              void* d_out, int out_size, void* d_ws, size_t ws_size,
                              hipStream_t stream) {
    const float* X   = (const float*)d_in[0];
    const float* Dyn = (const float*)d_in[1];
    const float* Wf  = (const float*)d_in[2];
    const float* Geo = (const float*)d_in[3];
    const float* KLm = (const float*)d_in[4];
    const float* Wd  = (const float*)d_in[5];
    const float* bdv = (const float*)d_in[6];
    float* out = (float*)d_out;

    _Float16* Xt = (_Float16*)d_ws;   // 2 MB scratch (ws verified >= 2MB, R4-R9)
    transposeX<<<dim3(8, Nn / 64), dim3(256), 0, stream>>>(X, Xt);
    fused_gcn<<<dim3(8 * (Nn / 16)), dim3(NT), 0, stream>>>(
        Xt, Dyn, Wf, Geo, KLm, Wd, bdv, out);
}